// Round 3
// baseline (474.927 us; speedup 1.0000x reference)
//
#include <hip/hip_runtime.h>
#include <hip/hip_bf16.h>
#include <math.h>

#define BATCH 16384
#define DDIM 64
#define HID 128
#define NP 2016   // DDIM*(DDIM-1)/2

typedef float f32x4 __attribute__((ext_vector_type(4)));
typedef __bf16 bf16x8 __attribute__((ext_vector_type(8)));
typedef unsigned short ushort8 __attribute__((ext_vector_type(8)));
typedef unsigned short ushort4v __attribute__((ext_vector_type(4)));

__device__ __forceinline__ unsigned short f32_to_bf16(float f) {
    union { float f; unsigned int u; } v; v.f = f;
    unsigned int u = v.u;
    u += 0x7FFFu + ((u >> 16) & 1u);   // round-to-nearest-even
    return (unsigned short)(u >> 16);
}
__device__ __forceinline__ float bf16_to_f32(unsigned short s) {
    union { unsigned int u; float f; } v; v.u = ((unsigned int)s) << 16;
    return v.f;
}

// ---------------------------------------------------------------------------
// Kernel 1: blocks [0,512): h = tanh(x @ W1^T + b1), split into bf16 hi/lo.
//           blocks [512,764): split W2 into bf16 hi/lo.
// ---------------------------------------------------------------------------
__global__ __launch_bounds__(256) void prep_kernel(
    const float* __restrict__ x, const float* __restrict__ W1,
    const float* __restrict__ b1, const float* __restrict__ W2,
    unsigned short* __restrict__ h_hi, unsigned short* __restrict__ h_lo,
    unsigned short* __restrict__ w2_hi, unsigned short* __restrict__ w2_lo)
{
    const int bid = blockIdx.x;
    const int t = threadIdx.x;

    if (bid >= 512) {
        // W2 split: 2016*128 = 258048 floats = 252 blocks * 256 thr * 4
        const int idx4 = ((bid - 512) * 256 + t) * 4;
        f32x4 v = *(const f32x4*)(W2 + idx4);
        ushort4v hi, lo;
#pragma unroll
        for (int e = 0; e < 4; ++e) {
            unsigned short h = f32_to_bf16(v[e]);
            hi[e] = h;
            lo[e] = f32_to_bf16(v[e] - bf16_to_f32(h));
        }
        *(ushort4v*)(w2_hi + idx4) = hi;
        *(ushort4v*)(w2_lo + idx4) = lo;
        return;
    }

    __shared__ float W1s[HID][68];   // pad 64->68 (16B-aligned rows)
    __shared__ float xs[32][68];

    const int rbase = bid * 32;
    // load W1 (128x64 f32): 2048 float4 chunks, 8 per thread
#pragma unroll
    for (int i = 0; i < 8; ++i) {
        int ch = t + i * 256;
        int o = ch >> 4, kc = ch & 15;
        f32x4 w = *(const f32x4*)(W1 + o * DDIM + kc * 4);
        *(f32x4*)&W1s[o][kc * 4] = w;
    }
    // load x tile (32x64 f32): 512 float4 chunks, 2 per thread
#pragma unroll
    for (int i = 0; i < 2; ++i) {
        int ch = t + i * 256;
        int r = ch >> 4, kc = ch & 15;
        f32x4 v = *(const f32x4*)(x + (rbase + r) * DDIM + kc * 4);
        *(f32x4*)&xs[r][kc * 4] = v;
    }
    __syncthreads();

    const int og = t & 31;          // o-group: o = og + 32*oo (strided -> 2-way banks)
    const int r0 = (t >> 5) * 4;    // 4 rows per thread
    float acc[4][4];
#pragma unroll
    for (int rr = 0; rr < 4; ++rr)
#pragma unroll
        for (int oo = 0; oo < 4; ++oo) acc[rr][oo] = 0.0f;

#pragma unroll
    for (int kc = 0; kc < 16; ++kc) {
        f32x4 w4[4], x4[4];
#pragma unroll
        for (int oo = 0; oo < 4; ++oo) w4[oo] = *(const f32x4*)&W1s[og + 32 * oo][kc * 4];
#pragma unroll
        for (int rr = 0; rr < 4; ++rr) x4[rr] = *(const f32x4*)&xs[r0 + rr][kc * 4];
#pragma unroll
        for (int rr = 0; rr < 4; ++rr)
#pragma unroll
            for (int oo = 0; oo < 4; ++oo)
                acc[rr][oo] += w4[oo][0] * x4[rr][0] + w4[oo][1] * x4[rr][1]
                             + w4[oo][2] * x4[rr][2] + w4[oo][3] * x4[rr][3];
    }

#pragma unroll
    for (int rr = 0; rr < 4; ++rr) {
        const int row = rbase + r0 + rr;
#pragma unroll
        for (int oo = 0; oo < 4; ++oo) {
            const int o = og + 32 * oo;
            float v = tanhf(acc[rr][oo] + b1[o]);
            unsigned short hi = f32_to_bf16(v);
            h_hi[row * HID + o] = hi;
            h_lo[row * HID + o] = f32_to_bf16(v - bf16_to_f32(hi));
        }
    }
}

// ---------------------------------------------------------------------------
// Kernel 2: params = h @ W2^T + b2 via split-bf16 MFMA (3-term), fused
// scatter into J (upper +v, lower -v), diag zeroed by nt==0 blocks.
// Tile: BM=128 (batch) x BN=64 (params), K=128 in two 64-wide stages.
// ---------------------------------------------------------------------------
#define BM 128
#define BN 64
#define PADK 72   // bf16 elems per LDS row (144 B, 16B-aligned, 2-way banks)

__global__ __launch_bounds__(256) void gemm2_kernel(
    const unsigned short* __restrict__ h_hi, const unsigned short* __restrict__ h_lo,
    const unsigned short* __restrict__ w2_hi, const unsigned short* __restrict__ w2_lo,
    const float* __restrict__ b2, float* __restrict__ out)
{
    // XCD-chunked swizzle (4096 % 8 == 0 -> bijective): one XCD owns 16
    // consecutive m-tiles with ALL their n-tiles -> partial J cache lines
    // from upper/lower scatter merge in that XCD's L2.
    const int bid = blockIdx.x;
    const int per = gridDim.x >> 3;
    const int nbid = (bid & 7) * per + (bid >> 3);
    const int mt = nbid >> 5;   // 0..127
    const int nt = nbid & 31;   // 0..31
    const int mbase = mt * BM;
    const int pbase = nt * BN;

    __shared__ unsigned short Ah[BM][PADK], Al[BM][PADK];
    __shared__ unsigned short Bh[BN][PADK], Bl[BN][PADK];

    const int t = threadIdx.x;
    const int lane = t & 63;
    const int wid = t >> 6;
    const int wm = wid >> 1, wn = wid & 1;   // 2x2 wave grid, 64m x 32n each

    f32x4 acc[4][2];
#pragma unroll
    for (int i = 0; i < 4; ++i)
#pragma unroll
        for (int j = 0; j < 2; ++j) acc[i][j] = (f32x4){0.f, 0.f, 0.f, 0.f};

    const int al = lane & 15;
    const int kl = (lane >> 4) * 8;

    for (int kt = 0; kt < 2; ++kt) {
        __syncthreads();
        // stage A (128 rows x 64 k, hi+lo): 1024 ushort8 chunks each, 4/thread
#pragma unroll
        for (int i = 0; i < 4; ++i) {
            int ch = t + i * 256;
            int m = ch >> 3, kc = ch & 7;
            const int gofs = (mbase + m) * HID + kt * 64 + kc * 8;
            *(ushort8*)&Ah[m][kc * 8] = *(const ushort8*)(h_hi + gofs);
            *(ushort8*)&Al[m][kc * 8] = *(const ushort8*)(h_lo + gofs);
        }
        // stage B (64 params x 64 k, hi+lo): 512 chunks each, 2/thread
#pragma unroll
        for (int i = 0; i < 2; ++i) {
            int ch = t + i * 256;
            int n = ch >> 3, kc = ch & 7;
            int p = pbase + n;
            ushort8 vh = {0, 0, 0, 0, 0, 0, 0, 0};
            ushort8 vl = {0, 0, 0, 0, 0, 0, 0, 0};
            if (p < NP) {
                const int gofs = p * HID + kt * 64 + kc * 8;
                vh = *(const ushort8*)(w2_hi + gofs);
                vl = *(const ushort8*)(w2_lo + gofs);
            }
            *(ushort8*)&Bh[n][kc * 8] = vh;
            *(ushort8*)&Bl[n][kc * 8] = vl;
        }
        __syncthreads();

#pragma unroll
        for (int ks = 0; ks < 2; ++ks) {
            bf16x8 ahi[4], alo[4], bhi[2], blo[2];
#pragma unroll
            for (int mi = 0; mi < 4; ++mi) {
                int m = wm * 64 + mi * 16 + al;
                ahi[mi] = *(const bf16x8*)&Ah[m][ks * 32 + kl];
                alo[mi] = *(const bf16x8*)&Al[m][ks * 32 + kl];
            }
#pragma unroll
            for (int ni = 0; ni < 2; ++ni) {
                int n = wn * 32 + ni * 16 + al;
                bhi[ni] = *(const bf16x8*)&Bh[n][ks * 32 + kl];
                blo[ni] = *(const bf16x8*)&Bl[n][ks * 32 + kl];
            }
#pragma unroll
            for (int mi = 0; mi < 4; ++mi)
#pragma unroll
                for (int ni = 0; ni < 2; ++ni) {
                    acc[mi][ni] = __builtin_amdgcn_mfma_f32_16x16x32_bf16(ahi[mi], bhi[ni], acc[mi][ni], 0, 0, 0);
                    acc[mi][ni] = __builtin_amdgcn_mfma_f32_16x16x32_bf16(ahi[mi], blo[ni], acc[mi][ni], 0, 0, 0);
                    acc[mi][ni] = __builtin_amdgcn_mfma_f32_16x16x32_bf16(alo[mi], bhi[ni], acc[mi][ni], 0, 0, 0);
                }
        }
    }

    // Epilogue: C/D layout: col = lane&15 (param), row = (lane>>4)*4 + r (batch)
    const int rq = lane >> 4;
#pragma unroll
    for (int ni = 0; ni < 2; ++ni) {
        const int p = pbase + wn * 32 + ni * 16 + al;
        if (p < NP) {
            // invert p -> (i,j): off(i) = i*(127-i)/2
            int i = (int)(63.5f - sqrtf(4032.25f - 2.0f * (float)p));
            while (i > 0 && i * (127 - i) / 2 > p) --i;
            while ((i + 1) * (126 - i) / 2 <= p) ++i;
            const int j = i + 1 + (p - i * (127 - i) / 2);
            const float bb = b2[p];
#pragma unroll
            for (int mi = 0; mi < 4; ++mi) {
                const int bq = mbase + wm * 64 + mi * 16 + rq * 4;
                f32x4 a = acc[mi][ni];
#pragma unroll
                for (int r = 0; r < 4; ++r) {
                    float v = a[r] + bb;
                    float* Jb = out + (size_t)(bq + r) * 4096;
                    Jb[i * 64 + j] = v;
                    Jb[j * 64 + i] = -v;
                }
            }
        }
    }
    // diagonal zeros: nt==0 blocks cover their 128 batch rows
    if (nt == 0) {
#pragma unroll
        for (int i2 = 0; i2 < 32; ++i2) {
            int dd = t + i2 * 256;          // 128 rows * 64 diag entries
            int r = dd >> 6, d = dd & 63;
            out[(size_t)(mbase + r) * 4096 + d * 65] = 0.0f;
        }
    }
}

// ---------------------------------------------------------------------------
extern "C" void kernel_launch(void* const* d_in, const int* in_sizes, int n_in,
                              void* d_out, int out_size, void* d_ws, size_t ws_size,
                              hipStream_t stream) {
    const float* x  = (const float*)d_in[0];
    const float* W1 = (const float*)d_in[1];
    const float* b1 = (const float*)d_in[2];
    const float* W2 = (const float*)d_in[3];
    const float* b2 = (const float*)d_in[4];
    float* out = (float*)d_out;

    unsigned short* h_hi  = (unsigned short*)d_ws;                 // 16384*128
    unsigned short* h_lo  = h_hi + (size_t)BATCH * HID;
    unsigned short* w2_hi = h_lo + (size_t)BATCH * HID;            // 2016*128
    unsigned short* w2_lo = w2_hi + (size_t)NP * HID;
    // total ws use: 2*(16384*128 + 2016*128)*2 B ≈ 9.0 MB

    prep_kernel<<<dim3(764), dim3(256), 0, stream>>>(x, W1, b1, W2, h_hi, h_lo, w2_hi, w2_lo);
    gemm2_kernel<<<dim3(4096), dim3(256), 0, stream>>>(h_hi, h_lo, w2_hi, w2_lo, b2, out);
}

// Round 10
// 382.794 us; speedup vs baseline: 1.2407x; 1.2407x over previous
//
#include <hip/hip_runtime.h>
#include <hip/hip_bf16.h>
#include <math.h>

#define BATCH 16384
#define DDIM 64
#define HID 128
#define NP 2016   // DDIM*(DDIM-1)/2

typedef float f32x4 __attribute__((ext_vector_type(4)));
typedef __bf16 bf16x8 __attribute__((ext_vector_type(8)));
typedef unsigned short ushort8 __attribute__((ext_vector_type(8)));
typedef unsigned short ushort4v __attribute__((ext_vector_type(4)));

__device__ __forceinline__ unsigned short f32_to_bf16(float f) {
    union { float f; unsigned int u; } v; v.f = f;
    unsigned int u = v.u;
    u += 0x7FFFu + ((u >> 16) & 1u);   // round-to-nearest-even
    return (unsigned short)(u >> 16);
}
__device__ __forceinline__ float bf16_to_f32(unsigned short s) {
    union { unsigned int u; float f; } v; v.u = ((unsigned int)s) << 16;
    return v.f;
}

// ---------------------------------------------------------------------------
// Kernel 1: blocks [0,512): h = tanh(x @ W1^T + b1), split into bf16 hi/lo.
//           blocks [512,764): split W2 into bf16 hi/lo.
// ---------------------------------------------------------------------------
__global__ __launch_bounds__(256) void prep_kernel(
    const float* __restrict__ x, const float* __restrict__ W1,
    const float* __restrict__ b1, const float* __restrict__ W2,
    unsigned short* __restrict__ h_hi, unsigned short* __restrict__ h_lo,
    unsigned short* __restrict__ w2_hi, unsigned short* __restrict__ w2_lo)
{
    const int bid = blockIdx.x;
    const int t = threadIdx.x;

    if (bid >= 512) {
        const int idx4 = ((bid - 512) * 256 + t) * 4;
        f32x4 v = *(const f32x4*)(W2 + idx4);
        ushort4v hi, lo;
#pragma unroll
        for (int e = 0; e < 4; ++e) {
            unsigned short h = f32_to_bf16(v[e]);
            hi[e] = h;
            lo[e] = f32_to_bf16(v[e] - bf16_to_f32(h));
        }
        *(ushort4v*)(w2_hi + idx4) = hi;
        *(ushort4v*)(w2_lo + idx4) = lo;
        return;
    }

    __shared__ float W1s[HID][68];
    __shared__ float xs[32][68];

    const int rbase = bid * 32;
#pragma unroll
    for (int i = 0; i < 8; ++i) {
        int ch = t + i * 256;
        int o = ch >> 4, kc = ch & 15;
        f32x4 w = *(const f32x4*)(W1 + o * DDIM + kc * 4);
        *(f32x4*)&W1s[o][kc * 4] = w;
    }
#pragma unroll
    for (int i = 0; i < 2; ++i) {
        int ch = t + i * 256;
        int r = ch >> 4, kc = ch & 15;
        f32x4 v = *(const f32x4*)(x + (rbase + r) * DDIM + kc * 4);
        *(f32x4*)&xs[r][kc * 4] = v;
    }
    __syncthreads();

    const int og = t & 31;
    const int r0 = (t >> 5) * 4;
    float acc[4][4];
#pragma unroll
    for (int rr = 0; rr < 4; ++rr)
#pragma unroll
        for (int oo = 0; oo < 4; ++oo) acc[rr][oo] = 0.0f;

#pragma unroll
    for (int kc = 0; kc < 16; ++kc) {
        f32x4 w4[4], x4[4];
#pragma unroll
        for (int oo = 0; oo < 4; ++oo) w4[oo] = *(const f32x4*)&W1s[og + 32 * oo][kc * 4];
#pragma unroll
        for (int rr = 0; rr < 4; ++rr) x4[rr] = *(const f32x4*)&xs[r0 + rr][kc * 4];
#pragma unroll
        for (int rr = 0; rr < 4; ++rr)
#pragma unroll
            for (int oo = 0; oo < 4; ++oo)
                acc[rr][oo] += w4[oo][0] * x4[rr][0] + w4[oo][1] * x4[rr][1]
                             + w4[oo][2] * x4[rr][2] + w4[oo][3] * x4[rr][3];
    }

#pragma unroll
    for (int rr = 0; rr < 4; ++rr) {
        const int row = rbase + r0 + rr;
#pragma unroll
        for (int oo = 0; oo < 4; ++oo) {
            const int o = og + 32 * oo;
            float v = tanhf(acc[rr][oo] + b1[o]);
            unsigned short hi = f32_to_bf16(v);
            h_hi[row * HID + o] = hi;
            h_lo[row * HID + o] = f32_to_bf16(v - bf16_to_f32(hi));
        }
    }
}

// ---------------------------------------------------------------------------
// Kernel 2: params = h @ W2^T + b2 via split-bf16 MFMA (3-term).
// Tile: BM=128 (batch) x BN=64 (params), K=128 in two 64-wide stages.
// FUSED=false: dense params write (for scatter pass). FUSED=true: direct J
// scatter (fallback when ws is too small).
// ---------------------------------------------------------------------------
#define BM 128
#define BN 64
#define PADK 72   // bf16 elems per LDS row (144 B, 16B-aligned, 2-way banks)

template <bool FUSED>
__global__ __launch_bounds__(256) void gemm2_tmpl(
    const unsigned short* __restrict__ h_hi, const unsigned short* __restrict__ h_lo,
    const unsigned short* __restrict__ w2_hi, const unsigned short* __restrict__ w2_lo,
    const float* __restrict__ b2, float* __restrict__ outp)
{
    // XCD-chunked swizzle (4096 % 8 == 0 -> bijective)
    const int bid = blockIdx.x;
    const int per = gridDim.x >> 3;
    const int nbid = (bid & 7) * per + (bid >> 3);
    const int mt = nbid >> 5;   // 0..127
    const int nt = nbid & 31;   // 0..31
    const int mbase = mt * BM;
    const int pbase = nt * BN;

    __shared__ unsigned short Ah[BM][PADK], Al[BM][PADK];
    __shared__ unsigned short Bh[BN][PADK], Bl[BN][PADK];

    const int t = threadIdx.x;
    const int lane = t & 63;
    const int wid = t >> 6;
    const int wm = wid >> 1, wn = wid & 1;   // 2x2 wave grid, 64m x 32n each

    f32x4 acc[4][2];
#pragma unroll
    for (int i = 0; i < 4; ++i)
#pragma unroll
        for (int j = 0; j < 2; ++j) acc[i][j] = (f32x4){0.f, 0.f, 0.f, 0.f};

    const int al = lane & 15;
    const int kl = (lane >> 4) * 8;

    for (int kt = 0; kt < 2; ++kt) {
        __syncthreads();
        // stage A (128 rows x 64 k, hi+lo): 1024 ushort8 chunks each, 4/thread
#pragma unroll
        for (int i = 0; i < 4; ++i) {
            int ch = t + i * 256;
            int m = ch >> 3, kc = ch & 7;
            const int gofs = (mbase + m) * HID + kt * 64 + kc * 8;
            *(ushort8*)&Ah[m][kc * 8] = *(const ushort8*)(h_hi + gofs);
            *(ushort8*)&Al[m][kc * 8] = *(const ushort8*)(h_lo + gofs);
        }
        // stage B (64 params x 64 k, hi+lo): 512 chunks each, 2/thread
#pragma unroll
        for (int i = 0; i < 2; ++i) {
            int ch = t + i * 256;
            int n = ch >> 3, kc = ch & 7;
            int p = pbase + n;
            ushort8 vh = {0, 0, 0, 0, 0, 0, 0, 0};
            ushort8 vl = {0, 0, 0, 0, 0, 0, 0, 0};
            if (p < NP) {
                const int gofs = p * HID + kt * 64 + kc * 8;
                vh = *(const ushort8*)(w2_hi + gofs);
                vl = *(const ushort8*)(w2_lo + gofs);
            }
            *(ushort8*)&Bh[n][kc * 8] = vh;
            *(ushort8*)&Bl[n][kc * 8] = vl;
        }
        __syncthreads();

#pragma unroll
        for (int ks = 0; ks < 2; ++ks) {
            bf16x8 ahi[4], alo[4], bhi[2], blo[2];
#pragma unroll
            for (int mi = 0; mi < 4; ++mi) {
                int m = wm * 64 + mi * 16 + al;
                ahi[mi] = *(const bf16x8*)&Ah[m][ks * 32 + kl];
                alo[mi] = *(const bf16x8*)&Al[m][ks * 32 + kl];
            }
#pragma unroll
            for (int ni = 0; ni < 2; ++ni) {
                int n = wn * 32 + ni * 16 + al;
                bhi[ni] = *(const bf16x8*)&Bh[n][ks * 32 + kl];
                blo[ni] = *(const bf16x8*)&Bl[n][ks * 32 + kl];
            }
#pragma unroll
            for (int mi = 0; mi < 4; ++mi)
#pragma unroll
                for (int ni = 0; ni < 2; ++ni) {
                    acc[mi][ni] = __builtin_amdgcn_mfma_f32_16x16x32_bf16(ahi[mi], bhi[ni], acc[mi][ni], 0, 0, 0);
                    acc[mi][ni] = __builtin_amdgcn_mfma_f32_16x16x32_bf16(ahi[mi], blo[ni], acc[mi][ni], 0, 0, 0);
                    acc[mi][ni] = __builtin_amdgcn_mfma_f32_16x16x32_bf16(alo[mi], bhi[ni], acc[mi][ni], 0, 0, 0);
                }
        }
    }

    // C/D layout: col = lane&15 (param), row = (lane>>4)*4 + r (batch)
    const int rq = lane >> 4;
    if constexpr (!FUSED) {
        // Dense params write: block covers p in [pbase,pbase+64) per row ->
        // two aligned 128B lines per row, full-line writes.
#pragma unroll
        for (int ni = 0; ni < 2; ++ni) {
            const int p = pbase + wn * 32 + ni * 16 + al;
            if (p < NP) {
                const float bb = b2[p];
#pragma unroll
                for (int mi = 0; mi < 4; ++mi) {
                    const int row0 = mbase + wm * 64 + mi * 16 + rq * 4;
                    f32x4 a = acc[mi][ni];
#pragma unroll
                    for (int r = 0; r < 4; ++r)
                        outp[(size_t)(row0 + r) * NP + p] = a[r] + bb;
                }
            }
        }
    } else {
#pragma unroll
        for (int ni = 0; ni < 2; ++ni) {
            const int p = pbase + wn * 32 + ni * 16 + al;
            if (p < NP) {
                int i = (int)(63.5f - sqrtf(4032.25f - 2.0f * (float)p));
                while (i > 0 && i * (127 - i) / 2 > p) --i;
                while ((i + 1) * (126 - i) / 2 <= p) ++i;
                const int j = i + 1 + (p - i * (127 - i) / 2);
                const float bb = b2[p];
#pragma unroll
                for (int mi = 0; mi < 4; ++mi) {
                    const int bq = mbase + wm * 64 + mi * 16 + rq * 4;
                    f32x4 a = acc[mi][ni];
#pragma unroll
                    for (int r = 0; r < 4; ++r) {
                        float v = a[r] + bb;
                        float* Jb = outp + (size_t)(bq + r) * 4096;
                        Jb[i * 64 + j] = v;
                        Jb[j * 64 + i] = -v;
                    }
                }
            }
        }
        if (nt == 0) {
#pragma unroll
            for (int i2 = 0; i2 < 32; ++i2) {
                int dd = t + i2 * 256;
                int r = dd >> 6, d = dd & 63;
                outp[(size_t)(mbase + r) * 4096 + d * 65] = 0.0f;
            }
        }
    }
}

// ---------------------------------------------------------------------------
// Kernel 3: scatter params -> J with fully-coalesced float4 row writes.
// ROWS batch rows per block, params staged in LDS (ROWS*2016*4 B).
// Within-probe A/B: ROWS=8 (63KB LDS, 2 blk/CU) vs ROWS=4 (31.5KB, 5 blk/CU)
// on disjoint halves of the batch — separate dispatches, separate counters.
// ---------------------------------------------------------------------------
template <int ROWS>
__global__ __launch_bounds__(256) void scatter_tmpl(
    const float* __restrict__ params, float* __restrict__ out, int row0)
{
    __shared__ float Pf[ROWS * NP];
    const int t = threadIdx.x;
    const size_t base_row = (size_t)row0 + (size_t)blockIdx.x * ROWS;

    // load ROWS rows of params: ROWS*504 float4 chunks, coalesced
    const f32x4* src = (const f32x4*)(params + base_row * NP);
    for (int ch = t; ch < ROWS * (NP / 4); ch += 256)
        *(f32x4*)&Pf[ch * 4] = src[ch];
    __syncthreads();

    f32x4* dst = (f32x4*)(out + base_row * 4096);
#pragma unroll
    for (int it = 0; it < ROWS * 4; ++it) {
        const int idx = it * 256 + t;     // 0 .. ROWS*1024-1 float4s
        const int b = idx >> 10;          // batch row within block
        const int rem = idx & 1023;
        const int i = rem >> 4;           // J row
        const int c = rem & 15;           // float4 within row
        const float* P = &Pf[b * NP];
        const int offi = i * (127 - i) / 2;
        f32x4 v;
#pragma unroll
        for (int e = 0; e < 4; ++e) {
            const int j = 4 * c + e;
            float r;
            if (j > i)       r =  P[offi + j - i - 1];
            else if (j < i)  r = -P[j * (127 - j) / 2 + i - j - 1];
            else             r = 0.0f;
            v[e] = r;
        }
        dst[idx] = v;
    }
}

// ---------------------------------------------------------------------------
extern "C" void kernel_launch(void* const* d_in, const int* in_sizes, int n_in,
                              void* d_out, int out_size, void* d_ws, size_t ws_size,
                              hipStream_t stream) {
    const float* x  = (const float*)d_in[0];
    const float* W1 = (const float*)d_in[1];
    const float* b1 = (const float*)d_in[2];
    const float* W2 = (const float*)d_in[3];
    const float* b2 = (const float*)d_in[4];
    float* out = (float*)d_out;

    unsigned short* h_hi  = (unsigned short*)d_ws;                 // 16384*128
    unsigned short* h_lo  = h_hi + (size_t)BATCH * HID;
    unsigned short* w2_hi = h_lo + (size_t)BATCH * HID;            // 2016*128
    unsigned short* w2_lo = w2_hi + (size_t)NP * HID;
    const size_t split_bytes = ((size_t)BATCH * HID + (size_t)NP * HID) * 2 * 2; // 9,420,800
    float* params = (float*)((char*)d_ws + split_bytes);           // 16384*2016 f32
    const size_t need = split_bytes + (size_t)BATCH * NP * 4;      // ~141.5 MB

    prep_kernel<<<dim3(764), dim3(256), 0, stream>>>(x, W1, b1, W2, h_hi, h_lo, w2_hi, w2_lo);
    if (ws_size >= need) {
        gemm2_tmpl<false><<<dim3(4096), dim3(256), 0, stream>>>(h_hi, h_lo, w2_hi, w2_lo, b2, params);
        // A/B: rows [0,8192) with 8-row blocks, rows [8192,16384) with 4-row blocks
        scatter_tmpl<8><<<dim3(1024), dim3(256), 0, stream>>>(params, out, 0);
        scatter_tmpl<4><<<dim3(2048), dim3(256), 0, stream>>>(params, out, 8192);
    } else {
        gemm2_tmpl<true><<<dim3(4096), dim3(256), 0, stream>>>(h_hi, h_lo, w2_hi, w2_lo, b2, out);
    }
}

// Round 18
// 364.896 us; speedup vs baseline: 1.3015x; 1.0490x over previous
//
#include <hip/hip_runtime.h>
#include <hip/hip_bf16.h>
#include <math.h>

#define BATCH 16384
#define DDIM 64
#define HID 128
#define NP 2016   // DDIM*(DDIM-1)/2

typedef float f32x4 __attribute__((ext_vector_type(4)));
typedef __bf16 bf16x8 __attribute__((ext_vector_type(8)));
typedef unsigned short ushort8 __attribute__((ext_vector_type(8)));
typedef unsigned short ushort4v __attribute__((ext_vector_type(4)));

__device__ __forceinline__ unsigned short f32_to_bf16(float f) {
    union { float f; unsigned int u; } v; v.f = f;
    unsigned int u = v.u;
    u += 0x7FFFu + ((u >> 16) & 1u);   // round-to-nearest-even
    return (unsigned short)(u >> 16);
}
__device__ __forceinline__ float bf16_to_f32(unsigned short s) {
    union { unsigned int u; float f; } v; v.u = ((unsigned int)s) << 16;
    return v.f;
}

// ---------------------------------------------------------------------------
// Kernel 1: blocks [0,512): h = tanh(x @ W1^T + b1), split into bf16 hi/lo.
//           blocks [512,764): split W2 into bf16 hi/lo.
// ---------------------------------------------------------------------------
__global__ __launch_bounds__(256) void prep_kernel(
    const float* __restrict__ x, const float* __restrict__ W1,
    const float* __restrict__ b1, const float* __restrict__ W2,
    unsigned short* __restrict__ h_hi, unsigned short* __restrict__ h_lo,
    unsigned short* __restrict__ w2_hi, unsigned short* __restrict__ w2_lo)
{
    const int bid = blockIdx.x;
    const int t = threadIdx.x;

    if (bid >= 512) {
        const int idx4 = ((bid - 512) * 256 + t) * 4;
        f32x4 v = *(const f32x4*)(W2 + idx4);
        ushort4v hi, lo;
#pragma unroll
        for (int e = 0; e < 4; ++e) {
            unsigned short h = f32_to_bf16(v[e]);
            hi[e] = h;
            lo[e] = f32_to_bf16(v[e] - bf16_to_f32(h));
        }
        *(ushort4v*)(w2_hi + idx4) = hi;
        *(ushort4v*)(w2_lo + idx4) = lo;
        return;
    }

    __shared__ float W1s[HID][68];
    __shared__ float xs[32][68];

    const int rbase = bid * 32;
#pragma unroll
    for (int i = 0; i < 8; ++i) {
        int ch = t + i * 256;
        int o = ch >> 4, kc = ch & 15;
        f32x4 w = *(const f32x4*)(W1 + o * DDIM + kc * 4);
        *(f32x4*)&W1s[o][kc * 4] = w;
    }
#pragma unroll
    for (int i = 0; i < 2; ++i) {
        int ch = t + i * 256;
        int r = ch >> 4, kc = ch & 15;
        f32x4 v = *(const f32x4*)(x + (rbase + r) * DDIM + kc * 4);
        *(f32x4*)&xs[r][kc * 4] = v;
    }
    __syncthreads();

    const int og = t & 31;
    const int r0 = (t >> 5) * 4;
    float acc[4][4];
#pragma unroll
    for (int rr = 0; rr < 4; ++rr)
#pragma unroll
        for (int oo = 0; oo < 4; ++oo) acc[rr][oo] = 0.0f;

#pragma unroll
    for (int kc = 0; kc < 16; ++kc) {
        f32x4 w4[4], x4[4];
#pragma unroll
        for (int oo = 0; oo < 4; ++oo) w4[oo] = *(const f32x4*)&W1s[og + 32 * oo][kc * 4];
#pragma unroll
        for (int rr = 0; rr < 4; ++rr) x4[rr] = *(const f32x4*)&xs[r0 + rr][kc * 4];
#pragma unroll
        for (int rr = 0; rr < 4; ++rr)
#pragma unroll
            for (int oo = 0; oo < 4; ++oo)
                acc[rr][oo] += w4[oo][0] * x4[rr][0] + w4[oo][1] * x4[rr][1]
                             + w4[oo][2] * x4[rr][2] + w4[oo][3] * x4[rr][3];
    }

#pragma unroll
    for (int rr = 0; rr < 4; ++rr) {
        const int row = rbase + r0 + rr;
#pragma unroll
        for (int oo = 0; oo < 4; ++oo) {
            const int o = og + 32 * oo;
            float v = tanhf(acc[rr][oo] + b1[o]);
            unsigned short hi = f32_to_bf16(v);
            h_hi[row * HID + o] = hi;
            h_lo[row * HID + o] = f32_to_bf16(v - bf16_to_f32(hi));
        }
    }
}

// ---------------------------------------------------------------------------
// Kernel 2: params = h @ W2^T + b2 via split-bf16 MFMA (3-term).
// Tile: BM=128 (batch) x BN=64 (params), K=128 in two 64-wide stages.
// FUSED=false: dense bf16 params write (for scatter pass). FUSED=true:
// direct f32 J scatter (fallback when ws is too small).
// ---------------------------------------------------------------------------
#define BM 128
#define BN 64
#define PADK 72   // bf16 elems per LDS row (144 B, 16B-aligned, 2-way banks)

template <bool FUSED>
__global__ __launch_bounds__(256) void gemm2_tmpl(
    const unsigned short* __restrict__ h_hi, const unsigned short* __restrict__ h_lo,
    const unsigned short* __restrict__ w2_hi, const unsigned short* __restrict__ w2_lo,
    const float* __restrict__ b2, void* __restrict__ outp)
{
    // XCD-chunked swizzle (4096 % 8 == 0 -> bijective)
    const int bid = blockIdx.x;
    const int per = gridDim.x >> 3;
    const int nbid = (bid & 7) * per + (bid >> 3);
    const int mt = nbid >> 5;   // 0..127
    const int nt = nbid & 31;   // 0..31
    const int mbase = mt * BM;
    const int pbase = nt * BN;

    __shared__ unsigned short Ah[BM][PADK], Al[BM][PADK];
    __shared__ unsigned short Bh[BN][PADK], Bl[BN][PADK];

    const int t = threadIdx.x;
    const int lane = t & 63;
    const int wid = t >> 6;
    const int wm = wid >> 1, wn = wid & 1;   // 2x2 wave grid, 64m x 32n each

    f32x4 acc[4][2];
#pragma unroll
    for (int i = 0; i < 4; ++i)
#pragma unroll
        for (int j = 0; j < 2; ++j) acc[i][j] = (f32x4){0.f, 0.f, 0.f, 0.f};

    const int al = lane & 15;
    const int kl = (lane >> 4) * 8;

    for (int kt = 0; kt < 2; ++kt) {
        __syncthreads();
        // stage A (128 rows x 64 k, hi+lo): 1024 ushort8 chunks each, 4/thread
#pragma unroll
        for (int i = 0; i < 4; ++i) {
            int ch = t + i * 256;
            int m = ch >> 3, kc = ch & 7;
            const int gofs = (mbase + m) * HID + kt * 64 + kc * 8;
            *(ushort8*)&Ah[m][kc * 8] = *(const ushort8*)(h_hi + gofs);
            *(ushort8*)&Al[m][kc * 8] = *(const ushort8*)(h_lo + gofs);
        }
        // stage B (64 params x 64 k, hi+lo): 512 chunks each, 2/thread
#pragma unroll
        for (int i = 0; i < 2; ++i) {
            int ch = t + i * 256;
            int n = ch >> 3, kc = ch & 7;
            int p = pbase + n;
            ushort8 vh = {0, 0, 0, 0, 0, 0, 0, 0};
            ushort8 vl = {0, 0, 0, 0, 0, 0, 0, 0};
            if (p < NP) {
                const int gofs = p * HID + kt * 64 + kc * 8;
                vh = *(const ushort8*)(w2_hi + gofs);
                vl = *(const ushort8*)(w2_lo + gofs);
            }
            *(ushort8*)&Bh[n][kc * 8] = vh;
            *(ushort8*)&Bl[n][kc * 8] = vl;
        }
        __syncthreads();

#pragma unroll
        for (int ks = 0; ks < 2; ++ks) {
            bf16x8 ahi[4], alo[4], bhi[2], blo[2];
#pragma unroll
            for (int mi = 0; mi < 4; ++mi) {
                int m = wm * 64 + mi * 16 + al;
                ahi[mi] = *(const bf16x8*)&Ah[m][ks * 32 + kl];
                alo[mi] = *(const bf16x8*)&Al[m][ks * 32 + kl];
            }
#pragma unroll
            for (int ni = 0; ni < 2; ++ni) {
                int n = wn * 32 + ni * 16 + al;
                bhi[ni] = *(const bf16x8*)&Bh[n][ks * 32 + kl];
                blo[ni] = *(const bf16x8*)&Bl[n][ks * 32 + kl];
            }
#pragma unroll
            for (int mi = 0; mi < 4; ++mi)
#pragma unroll
                for (int ni = 0; ni < 2; ++ni) {
                    acc[mi][ni] = __builtin_amdgcn_mfma_f32_16x16x32_bf16(ahi[mi], bhi[ni], acc[mi][ni], 0, 0, 0);
                    acc[mi][ni] = __builtin_amdgcn_mfma_f32_16x16x32_bf16(ahi[mi], blo[ni], acc[mi][ni], 0, 0, 0);
                    acc[mi][ni] = __builtin_amdgcn_mfma_f32_16x16x32_bf16(alo[mi], bhi[ni], acc[mi][ni], 0, 0, 0);
                }
        }
    }

    // C/D layout: col = lane&15 (param), row = (lane>>4)*4 + r (batch)
    const int rq = lane >> 4;
    if constexpr (!FUSED) {
        // Dense bf16 params write: block covers p in [pbase,pbase+64) per row.
        unsigned short* pw = (unsigned short*)outp;
#pragma unroll
        for (int ni = 0; ni < 2; ++ni) {
            const int p = pbase + wn * 32 + ni * 16 + al;
            if (p < NP) {
                const float bb = b2[p];
#pragma unroll
                for (int mi = 0; mi < 4; ++mi) {
                    const int row0 = mbase + wm * 64 + mi * 16 + rq * 4;
                    f32x4 a = acc[mi][ni];
#pragma unroll
                    for (int r = 0; r < 4; ++r)
                        pw[(size_t)(row0 + r) * NP + p] = f32_to_bf16(a[r] + bb);
                }
            }
        }
    } else {
        float* out = (float*)outp;
#pragma unroll
        for (int ni = 0; ni < 2; ++ni) {
            const int p = pbase + wn * 32 + ni * 16 + al;
            if (p < NP) {
                int i = (int)(63.5f - sqrtf(4032.25f - 2.0f * (float)p));
                while (i > 0 && i * (127 - i) / 2 > p) --i;
                while ((i + 1) * (126 - i) / 2 <= p) ++i;
                const int j = i + 1 + (p - i * (127 - i) / 2);
                const float bb = b2[p];
#pragma unroll
                for (int mi = 0; mi < 4; ++mi) {
                    const int bq = mbase + wm * 64 + mi * 16 + rq * 4;
                    f32x4 a = acc[mi][ni];
#pragma unroll
                    for (int r = 0; r < 4; ++r) {
                        float v = a[r] + bb;
                        float* Jb = out + (size_t)(bq + r) * 4096;
                        Jb[i * 64 + j] = v;
                        Jb[j * 64 + i] = -v;
                    }
                }
            }
        }
        if (nt == 0) {
#pragma unroll
            for (int i2 = 0; i2 < 32; ++i2) {
                int dd = t + i2 * 256;
                int r = dd >> 6, d = dd & 63;
                out[(size_t)(mbase + r) * 4096 + d * 65] = 0.0f;
            }
        }
    }
}

// ---------------------------------------------------------------------------
// Kernel 3: scatter bf16 params -> f32 J with fully-coalesced float4 writes.
// ROWS batch rows per block, params staged in LDS (ROWS*2016*2 B).
// Within-probe A/B: ROWS=8 (31.5KB LDS) vs ROWS=4 (15.75KB) on disjoint
// halves of the batch — separate dispatches, separate counters.
// ---------------------------------------------------------------------------
template <int ROWS>
__global__ __launch_bounds__(256) void scatter_tmpl(
    const unsigned short* __restrict__ params, float* __restrict__ out, int row0)
{
    __shared__ unsigned short Pf[ROWS * NP];
    const int t = threadIdx.x;
    const size_t base_row = (size_t)row0 + (size_t)blockIdx.x * ROWS;

    // load ROWS rows of bf16 params: ROWS*252 ushort8 chunks, coalesced
    const ushort8* src = (const ushort8*)(params + base_row * NP);
    for (int ch = t; ch < ROWS * (NP / 8); ch += 256)
        *(ushort8*)&Pf[ch * 8] = src[ch];
    __syncthreads();

    f32x4* dst = (f32x4*)(out + base_row * 4096);
#pragma unroll
    for (int it = 0; it < ROWS * 4; ++it) {
        const int idx = it * 256 + t;     // 0 .. ROWS*1024-1 float4s
        const int b = idx >> 10;          // batch row within block
        const int rem = idx & 1023;
        const int i = rem >> 4;           // J row
        const int c = rem & 15;           // float4 within row
        const unsigned short* P = &Pf[b * NP];
        const int offi = i * (127 - i) / 2;
        f32x4 v;
#pragma unroll
        for (int e = 0; e < 4; ++e) {
            const int j = 4 * c + e;
            float r;
            if (j > i)       r =  bf16_to_f32(P[offi + j - i - 1]);
            else if (j < i)  r = -bf16_to_f32(P[j * (127 - j) / 2 + i - j - 1]);
            else             r = 0.0f;
            v[e] = r;
        }
        dst[idx] = v;
    }
}

// ---------------------------------------------------------------------------
extern "C" void kernel_launch(void* const* d_in, const int* in_sizes, int n_in,
                              void* d_out, int out_size, void* d_ws, size_t ws_size,
                              hipStream_t stream) {
    const float* x  = (const float*)d_in[0];
    const float* W1 = (const float*)d_in[1];
    const float* b1 = (const float*)d_in[2];
    const float* W2 = (const float*)d_in[3];
    const float* b2 = (const float*)d_in[4];
    float* out = (float*)d_out;

    unsigned short* h_hi  = (unsigned short*)d_ws;                 // 16384*128
    unsigned short* h_lo  = h_hi + (size_t)BATCH * HID;
    unsigned short* w2_hi = h_lo + (size_t)BATCH * HID;            // 2016*128
    unsigned short* w2_lo = w2_hi + (size_t)NP * HID;
    const size_t split_bytes = ((size_t)BATCH * HID + (size_t)NP * HID) * 2 * 2; // 9,420,800 (16B-mult)
    unsigned short* params = (unsigned short*)((char*)d_ws + split_bytes);       // 16384*2016 bf16
    const size_t need = split_bytes + (size_t)BATCH * NP * 2;      // ~75.5 MB

    prep_kernel<<<dim3(764), dim3(256), 0, stream>>>(x, W1, b1, W2, h_hi, h_lo, w2_hi, w2_lo);
    if (ws_size >= need) {
        gemm2_tmpl<false><<<dim3(4096), dim3(256), 0, stream>>>(h_hi, h_lo, w2_hi, w2_lo, b2, (void*)params);
        // A/B: rows [0,8192) with 8-row blocks, rows [8192,16384) with 4-row blocks
        scatter_tmpl<8><<<dim3(1024), dim3(256), 0, stream>>>(params, out, 0);
        scatter_tmpl<4><<<dim3(2048), dim3(256), 0, stream>>>(params, out, 8192);
    } else {
        gemm2_tmpl<true><<<dim3(4096), dim3(256), 0, stream>>>(h_hi, h_lo, w2_hi, w2_lo, b2, (void*)out);
    }
}